// Round 2
// baseline (431.178 us; speedup 1.0000x reference)
//
#include <hip/hip_runtime.h>
#include <hip/hip_bf16.h>

// GAT layer: B=8, N=8 (BN=64 batches), Nodes=512, IF=OF=256.
// Input dtype (bf16 vs fp32) detected at runtime from data statistics;
// output written in the same mode. adj is int32 either way.
//
// Pipeline:
//  K0: detect dtype -> flag in ws
//  KA: Wh[bn,i,f] = sum_k h[bn,i,k]*W[k,f]  (fp32 accum -> bf16 in ws)
//      src/dst = Wh . a1 / Wh . a2          (from fp32 accum, stored fp32)
//  KB: e=leaky_relu(src_i+dst_j), mask, softmax, out=elu(att@Wh)

#define ALPHA 0.2f
#define MASK_VAL -9000000000000000.0f
#define NODES 512
#define FDIM 256
#define ROWS 16
#define BN 64

typedef __hip_bfloat16 bf16;

__device__ __forceinline__ float b2f(bf16 x) { return __bfloat162float(x); }

// ---------------- K0: dtype detect ----------------
__global__ __launch_bounds__(256) void detect_kernel(const unsigned short* __restrict__ hraw,
                                                     int* __restrict__ flag)
{
    const int tid = threadIdx.x;
    float m = 0.0f;
    for (int i = tid; i < 16384; i += 256) {
        unsigned int w = ((unsigned int)hraw[i]) << 16;   // interpret as bf16
        float v = __uint_as_float(w);
        v = fabsf(v);
        if (!(v == v)) v = 1e30f;                          // NaN -> huge
        m = fmaxf(m, v);
    }
    #pragma unroll
    for (int off = 32; off >= 1; off >>= 1)
        m = fmaxf(m, __shfl_down(m, off));
    __shared__ float red[4];
    if ((tid & 63) == 0) red[tid >> 6] = m;
    __syncthreads();
    if (tid == 0) {
        float mm = fmaxf(fmaxf(red[0], red[1]), fmaxf(red[2], red[3]));
        *flag = (mm > 1e4f) ? 1 : 0;   // 1 = data is really fp32
    }
}

// ---------------- KA: Wh + src/dst ----------------
__global__ __launch_bounds__(256) void wh_kernel(
    const void* __restrict__ hv, const void* __restrict__ Wv, const void* __restrict__ av,
    const int* __restrict__ flagp,
    bf16* __restrict__ Wh, float* __restrict__ src, float* __restrict__ dst)
{
    const int flag = *flagp;
    const int bn  = blockIdx.y;
    const int i0  = blockIdx.x * ROWS;
    const int tid = threadIdx.x;

    __shared__ float hs[ROWS][FDIM];
    __shared__ float red1[ROWS][4];
    __shared__ float red2[ROWS][4];

    const size_t hbase = ((size_t)bn * NODES + i0) * FDIM;
    if (flag) {
        const float* hrow = (const float*)hv + hbase;
        #pragma unroll
        for (int r = 0; r < ROWS; ++r) hs[r][tid] = hrow[r * FDIM + tid];
    } else {
        const bf16* hrow = (const bf16*)hv + hbase;
        #pragma unroll
        for (int r = 0; r < ROWS; ++r) hs[r][tid] = b2f(hrow[r * FDIM + tid]);
    }
    __syncthreads();

    float acc[ROWS];
    #pragma unroll
    for (int r = 0; r < ROWS; ++r) acc[r] = 0.0f;

    if (flag) {
        const float* Wf = (const float*)Wv;
        for (int k = 0; k < FDIM; ++k) {
            float wv = Wf[k * FDIM + tid];
            #pragma unroll
            for (int r = 0; r < ROWS; ++r) acc[r] = fmaf(hs[r][k], wv, acc[r]);
        }
    } else {
        const bf16* Wb = (const bf16*)Wv;
        for (int k = 0; k < FDIM; ++k) {
            float wv = b2f(Wb[k * FDIM + tid]);
            #pragma unroll
            for (int r = 0; r < ROWS; ++r) acc[r] = fmaf(hs[r][k], wv, acc[r]);
        }
    }

    bf16* whrow = Wh + hbase;
    #pragma unroll
    for (int r = 0; r < ROWS; ++r)
        whrow[r * FDIM + tid] = __float2bfloat16(acc[r]);

    float a1, a2;
    if (flag) {
        a1 = ((const float*)av)[tid];
        a2 = ((const float*)av)[FDIM + tid];
    } else {
        a1 = b2f(((const bf16*)av)[tid]);
        a2 = b2f(((const bf16*)av)[FDIM + tid]);
    }

    const int lane = tid & 63, wave = tid >> 6;
    #pragma unroll
    for (int r = 0; r < ROWS; ++r) {
        float v1 = acc[r] * a1;
        float v2 = acc[r] * a2;
        #pragma unroll
        for (int off = 32; off >= 1; off >>= 1) {
            v1 += __shfl_down(v1, off);
            v2 += __shfl_down(v2, off);
        }
        if (lane == 0) { red1[r][wave] = v1; red2[r][wave] = v2; }
    }
    __syncthreads();
    if (tid < ROWS) {
        src[bn * NODES + i0 + tid] = red1[tid][0] + red1[tid][1] + red1[tid][2] + red1[tid][3];
        dst[bn * NODES + i0 + tid] = red2[tid][0] + red2[tid][1] + red2[tid][2] + red2[tid][3];
    }
}

// ---------------- KB: mask + softmax + att@Wh + elu ----------------
__global__ __launch_bounds__(256) void attn_kernel(
    const bf16* __restrict__ Wh, const float* __restrict__ src, const float* __restrict__ dst,
    const int* __restrict__ adj, const int* __restrict__ flagp, void* __restrict__ out)
{
    const int flag = *flagp;
    const int bn  = blockIdx.y;
    const int i0  = blockIdx.x * ROWS;
    const int tid = threadIdx.x;

    __shared__ float att[ROWS][NODES];   // 32 KB
    __shared__ float red[ROWS][4];
    __shared__ float rowstat[ROWS];

    const float* dstrow = dst + bn * NODES;
    for (int idx = tid; idx < ROWS * NODES; idx += 256) {
        int r = idx >> 9;
        int j = idx & (NODES - 1);
        float e = src[bn * NODES + i0 + r] + dstrow[j];
        e = (e > 0.0f) ? e : ALPHA * e;
        att[r][j] = (adj[(i0 + r) * NODES + j] > 0) ? e : MASK_VAL;
    }
    __syncthreads();

    const int lane = tid & 63, wave = tid >> 6;

    #pragma unroll
    for (int r = 0; r < ROWS; ++r) {
        float v = fmaxf(att[r][tid], att[r][tid + 256]);
        #pragma unroll
        for (int off = 32; off >= 1; off >>= 1)
            v = fmaxf(v, __shfl_down(v, off));
        if (lane == 0) red[r][wave] = v;
    }
    __syncthreads();
    if (tid < ROWS)
        rowstat[tid] = fmaxf(fmaxf(red[tid][0], red[tid][1]),
                             fmaxf(red[tid][2], red[tid][3]));
    __syncthreads();

    for (int idx = tid; idx < ROWS * NODES; idx += 256) {
        int r = idx >> 9;
        int j = idx & (NODES - 1);
        att[r][j] = __expf(att[r][j] - rowstat[r]);
    }
    __syncthreads();

    #pragma unroll
    for (int r = 0; r < ROWS; ++r) {
        float v = att[r][tid] + att[r][tid + 256];
        #pragma unroll
        for (int off = 32; off >= 1; off >>= 1)
            v += __shfl_down(v, off);
        if (lane == 0) red[r][wave] = v;
    }
    __syncthreads();
    if (tid < ROWS)
        rowstat[tid] = 1.0f / (red[tid][0] + red[tid][1] + red[tid][2] + red[tid][3]);
    __syncthreads();

    float acc[ROWS];
    #pragma unroll
    for (int r = 0; r < ROWS; ++r) acc[r] = 0.0f;

    const bf16* whb = Wh + (size_t)bn * NODES * FDIM;
    for (int j = 0; j < NODES; ++j) {
        float w = b2f(whb[j * FDIM + tid]);
        #pragma unroll
        for (int r = 0; r < ROWS; ++r)
            acc[r] = fmaf(att[r][j], w, acc[r]);
    }

    const size_t obase = ((size_t)bn * NODES + i0) * FDIM;
    if (flag) {
        float* outf = (float*)out + obase;
        #pragma unroll
        for (int r = 0; r < ROWS; ++r) {
            float v = acc[r] * rowstat[r];
            v = (v > 0.0f) ? v : expm1f(v);
            outf[r * FDIM + tid] = v;
        }
    } else {
        bf16* outb = (bf16*)out + obase;
        #pragma unroll
        for (int r = 0; r < ROWS; ++r) {
            float v = acc[r] * rowstat[r];
            v = (v > 0.0f) ? v : expm1f(v);
            outb[r * FDIM + tid] = __float2bfloat16(v);
        }
    }
}

extern "C" void kernel_launch(void* const* d_in, const int* in_sizes, int n_in,
                              void* d_out, int out_size, void* d_ws, size_t ws_size,
                              hipStream_t stream)
{
    const void* h   = d_in[0];
    const int*  adj = (const int*)d_in[1];
    const void* W   = d_in[2];
    const void* a   = d_in[3];

    // ws layout: [0..63] int flag pad | src fp32 32K | dst fp32 32K | Wh bf16 8.4M elems
    int*   flag = (int*)d_ws;
    float* src  = (float*)d_ws + 64;
    float* dst  = src + BN * NODES;
    bf16*  Wh   = (bf16*)(dst + BN * NODES);
    // total = 256 + 2*131072 + 16777216 bytes ~= 17.04 MB

    detect_kernel<<<1, 256, 0, stream>>>((const unsigned short*)h, flag);
    dim3 grid(NODES / ROWS, BN);   // (32, 64)
    wh_kernel<<<grid, 256, 0, stream>>>(h, W, a, flag, Wh, src, dst);
    attn_kernel<<<grid, 256, 0, stream>>>(Wh, src, dst, adj, flag, d_out);
}